// Round 14
// baseline (5289.811 us; speedup 1.0000x reference)
//
#include <hip/hip_runtime.h>
#include <hip/hip_bf16.h>
#include <math.h>

namespace {
constexpr int CB = 8;      // batch
constexpr int CS = 1024;   // seq
constexpr int CD = 1024;   // d_model
constexpr int CDH = 64;    // head dim
constexpr int CK = 16;     // neuron_k
constexpr int CN = 2048;   // n_neurons
constexpr int CNB = 32;    // n_basis
constexpr int CBR = 64;    // basis_rank
constexpr int CFF = 4096;  // d_ff
constexpr int CRH = 256;   // token residual hidden
constexpr int CT = CB * CS;  // 8192 tokens
constexpr int HP = 4;        // heads per outer iteration
constexpr int SLICE = 1024;  // tokens per scores/topk slice
constexpr int NCAND = 32;    // prescreen candidates
}

using f32x4v = __attribute__((ext_vector_type(4))) float;
using short8 = __attribute__((ext_vector_type(8))) short;

__device__ __forceinline__ unsigned short f2bf(float f) {
  unsigned u = __builtin_bit_cast(unsigned, f);
  u = (u + 0x7FFFu + ((u >> 16) & 1u)) >> 16;
  return (unsigned short)u;
}

// ---- fast double exp: Cody-Waite + degree-12 Taylor, rel err ~2e-16 ----
__device__ __forceinline__ double fexp64(double x) {
  x = fmin(fmax(x, -700.0), 700.0);
  const double kd = rint(x * 1.4426950408889634074);
  double r = fma(-kd, 6.93147180369123816490e-01, x);
  r = fma(-kd, 1.90821492927058770002e-10, r);
  double p = 2.087675698786810e-9;
  p = fma(p, r, 2.505210838544172e-8);
  p = fma(p, r, 2.755731922398589e-7);
  p = fma(p, r, 2.755731922398589e-6);
  p = fma(p, r, 2.480158730158730e-5);
  p = fma(p, r, 1.984126984126984e-4);
  p = fma(p, r, 1.388888888888889e-3);
  p = fma(p, r, 8.333333333333333e-3);
  p = fma(p, r, 4.166666666666666e-2);
  p = fma(p, r, 1.666666666666667e-1);
  p = fma(p, r, 0.5);
  p = fma(p, r, 1.0);
  p = fma(p, r, 1.0);
  const long long ki = (long long)kd;
  return p * __longlong_as_double((ki + 1023LL) << 52);
}

// ---------------- LayerNorm ----------------
template <typename TOUT>
__global__ __launch_bounds__(256) void ln_kernel(const float* __restrict__ x,
                                                 const float* __restrict__ g,
                                                 const float* __restrict__ be,
                                                 TOUT* __restrict__ out) {
  const int t = blockIdx.x, tid = threadIdx.x;
  const float4 v = reinterpret_cast<const float4*>(x + (size_t)t * CD)[tid];
  double s = (double)v.x + (double)v.y + (double)v.z + (double)v.w;
  double ss = (double)v.x * v.x + (double)v.y * v.y + (double)v.z * v.z + (double)v.w * v.w;
  for (int o = 32; o > 0; o >>= 1) { s += __shfl_down(s, o); ss += __shfl_down(ss, o); }
  __shared__ double sh[8];
  if ((tid & 63) == 0) { sh[tid >> 6] = s; sh[4 + (tid >> 6)] = ss; }
  __syncthreads();
  const double st = sh[0] + sh[1] + sh[2] + sh[3];
  const double sq = sh[4] + sh[5] + sh[6] + sh[7];
  const double mean = st * (1.0 / CD);
  const double var = sq * (1.0 / CD) - mean * mean;
  const double rstd = 1.0 / sqrt(var + 1e-5);
  const int d0 = tid * 4;
  TOUT* o4 = out + (size_t)t * CD + d0;
  o4[0] = (TOUT)((((double)v.x) - mean) * rstd * (double)g[d0 + 0] + (double)be[d0 + 0]);
  o4[1] = (TOUT)((((double)v.y) - mean) * rstd * (double)g[d0 + 1] + (double)be[d0 + 1]);
  o4[2] = (TOUT)((((double)v.z) - mean) * rstd * (double)g[d0 + 2] + (double)be[d0 + 2]);
  o4[3] = (TOUT)((((double)v.w) - mean) * rstd * (double)g[d0 + 3] + (double)be[d0 + 3]);
}

// ---------------- neurons = nA @ nB (f64) + f32 + bf16 copies ----------------
__global__ __launch_bounds__(256) void neurons_kernel(const float* __restrict__ nA,
                                                      const float* __restrict__ nB,
                                                      double* __restrict__ n64,
                                                      float* __restrict__ n32,
                                                      unsigned short* __restrict__ nbf) {
  const int j = blockIdx.y;
  const int d = blockIdx.x * 256 + threadIdx.x;
  double acc = 0.0;
#pragma unroll
  for (int r = 0; r < 32; ++r)
    acc += (double)nA[j * 32 + r] * (double)nB[r * CD + d];
  n64[(size_t)j * CD + d] = acc;
  const float f = (float)acc;
  n32[(size_t)j * CD + d] = f;
  nbf[(size_t)j * CD + d] = f2bf(f);
}

// ---------------- fused f64 QKV gemm, z-specialized waves (r13 config) ----------------
__global__ __launch_bounds__(768) void qkv64_z(
    const double* __restrict__ n64, const float* __restrict__ Wq,
    const float* __restrict__ Wk, const float* __restrict__ Wv,
    const float* __restrict__ bq, const float* __restrict__ bk,
    const float* __restrict__ bv, int h0, double* __restrict__ qkv2) {
  const int hh = blockIdx.x, bm = blockIdx.y * 64;
  const int cbase = (h0 + hh) * 64;
  const int tid = threadIdx.x;
  const int wv = tid >> 6, lane = tid & 63;
  const int z = wv >> 2, w2 = wv & 3;
  const int tx = lane & 15, ty = w2 * 4 + (lane >> 4);  // ty in 0..15
  __shared__ double aT[16][65];
  __shared__ double bsd[3][16][64];
  double acc[4][4] = {};
  const int lr = (tid & 255) >> 2, lk = (tid & 3) * 4;
  const int zz = tid >> 8, t2 = tid & 255, br = t2 >> 4, bc = (t2 & 15) * 4;
  const float* Wz = (zz == 0) ? Wq : ((zz == 1) ? Wk : Wv);
  for (int k0 = 0; k0 < CD; k0 += 16) {
    if (tid < 256) {
      const double2* p = reinterpret_cast<const double2*>(n64 + (size_t)(bm + lr) * CD + k0 + lk);
      double2 a0 = p[0], a1 = p[1];
      aT[lk + 0][lr] = a0.x; aT[lk + 1][lr] = a0.y;
      aT[lk + 2][lr] = a1.x; aT[lk + 3][lr] = a1.y;
    }
    {
      const float4 bf = *reinterpret_cast<const float4*>(Wz + (size_t)(k0 + br) * CD + cbase + bc);
      bsd[zz][br][bc + 0] = (double)bf.x; bsd[zz][br][bc + 1] = (double)bf.y;
      bsd[zz][br][bc + 2] = (double)bf.z; bsd[zz][br][bc + 3] = (double)bf.w;
    }
    __syncthreads();
#pragma unroll
    for (int kk = 0; kk < 16; ++kk) {
      double a[4];
#pragma unroll
      for (int i = 0; i < 4; ++i) a[i] = aT[kk][ty * 4 + i];
      const double2 b01 = *reinterpret_cast<const double2*>(&bsd[z][kk][tx * 4]);
      const double2 b23 = *reinterpret_cast<const double2*>(&bsd[z][kk][tx * 4 + 2]);
      const double b0 = b01.x, b1 = b01.y, b2 = b23.x, b3 = b23.y;
#pragma unroll
      for (int i = 0; i < 4; ++i) {
        acc[i][0] = fma(a[i], b0, acc[i][0]);
        acc[i][1] = fma(a[i], b1, acc[i][1]);
        acc[i][2] = fma(a[i], b2, acc[i][2]);
        acc[i][3] = fma(a[i], b3, acc[i][3]);
      }
    }
    __syncthreads();
  }
  const float* bb = (z == 0) ? bq : ((z == 1) ? bk : bv);
  double* outp = qkv2 + (size_t)(z * HP + hh) * CT * CDH;
#pragma unroll
  for (int i = 0; i < 4; ++i)
#pragma unroll
    for (int j = 0; j < 4; ++j)
      outp[(size_t)(bm + ty * 4 + i) * CDH + tx * 4 + j] =
          acc[i][j] + (double)bb[cbase + tx * 4 + j];
}

// ---------------- f64 attention v4: 512 threads, 2 q-rows/group ----------------
// Bit-identical math to v2 (same c-loop, same 16-lane xor tree, same kc-loop);
// only the thread-to-row mapping changes (4 waves -> 8 waves per block).
__global__ __launch_bounds__(512) void attn64_v4(const double* __restrict__ qkv2,
                                                 int h0, double* __restrict__ ctx64) {
  const int qt = blockIdx.x, b = blockIdx.y, hh = blockIdx.z;
  const int tid = threadIdx.x;
  const int tq = tid >> 4, tk = tid & 15;   // tq 0..31, 2 rows each
  const double* qp = qkv2 + ((size_t)(0 * HP + hh) * CT + (size_t)b * CS) * CDH;
  const double* kp = qkv2 + ((size_t)(1 * HP + hh) * CT + (size_t)b * CS) * CDH;
  const double* vp = qkv2 + ((size_t)(2 * HP + hh) * CT + (size_t)b * CS) * CDH;
  __shared__ double qT[64][66];   // [d][qrow]
  __shared__ double kps[64][35];  // K as [d][kc], then P as [qrow][kc] (35-pad: conflict fix)
  __shared__ double vsd[32][66];  // [kc][d]
  __shared__ double rowl[64];
  for (int it = 0; it < 8; ++it) {
    const int idx = it * 512 + tid, r = idx >> 6, d = idx & 63;
    qT[d][r] = qp[(size_t)(qt * 64 + r) * CDH + d];
  }
  if (tid < 64) rowl[tid] = 0.0;
  double od[2][4] = {};
  const int q0 = tq * 2, k0c = tk * 2, d0 = tk * 4;
  for (int kt = 0; kt < CS / 32; ++kt) {
    __syncthreads();
    for (int it = 0; it < 4; ++it) {
      const int idx = it * 512 + tid, kc = idx >> 6, d = idx & 63;
      kps[d][kc] = kp[(size_t)(kt * 32 + kc) * CDH + d];
      vsd[kc][d] = vp[(size_t)(kt * 32 + kc) * CDH + d];
    }
    __syncthreads();
    double s[2][2] = {};
#pragma unroll 4
    for (int c = 0; c < 64; ++c) {
      const double a0 = qT[c][q0], a1 = qT[c][q0 + 1];
      const double b0 = kps[c][k0c], b1 = kps[c][k0c + 1];
      s[0][0] = fma(a0, b0, s[0][0]); s[0][1] = fma(a0, b1, s[0][1]);
      s[1][0] = fma(a1, b0, s[1][0]); s[1][1] = fma(a1, b1, s[1][1]);
    }
    __syncthreads();  // all QK reads of kps done before P overwrites it
    double pr[2][2], rsum[2];
#pragma unroll
    for (int i = 0; i < 2; ++i) {
      pr[i][0] = fexp64(s[i][0] * 0.125);
      pr[i][1] = fexp64(s[i][1] * 0.125);
      rsum[i] = pr[i][0] + pr[i][1];
    }
#pragma unroll
    for (int off = 1; off <= 8; off <<= 1)
#pragma unroll
      for (int i = 0; i < 2; ++i) rsum[i] += __shfl_xor(rsum[i], off);
    if (tk == 0) {
#pragma unroll
      for (int i = 0; i < 2; ++i) rowl[q0 + i] += rsum[i];
    }
#pragma unroll
    for (int i = 0; i < 2; ++i) {
      kps[q0 + i][k0c] = pr[i][0];
      kps[q0 + i][k0c + 1] = pr[i][1];
    }
    __syncthreads();  // P visible
#pragma unroll 4
    for (int kc = 0; kc < 32; ++kc) {
      const double pa0 = kps[q0][kc], pa1 = kps[q0 + 1][kc];
      const double v0 = vsd[kc][d0], v1 = vsd[kc][d0 + 1];
      const double v2 = vsd[kc][d0 + 2], v3 = vsd[kc][d0 + 3];
      od[0][0] = fma(pa0, v0, od[0][0]); od[0][1] = fma(pa0, v1, od[0][1]);
      od[0][2] = fma(pa0, v2, od[0][2]); od[0][3] = fma(pa0, v3, od[0][3]);
      od[1][0] = fma(pa1, v0, od[1][0]); od[1][1] = fma(pa1, v1, od[1][1]);
      od[1][2] = fma(pa1, v2, od[1][2]); od[1][3] = fma(pa1, v3, od[1][3]);
    }
  }
  __syncthreads();
  double* cp = ctx64 + (size_t)b * CS * CD + (size_t)(h0 + hh) * CDH;
#pragma unroll
  for (int i = 0; i < 2; ++i) {
    const double inv = 1.0 / rowl[q0 + i];
    const size_t rbase = (size_t)(qt * 64 + q0 + i) * CD;
#pragma unroll
    for (int j = 0; j < 4; ++j) cp[rbase + d0 + j] = od[i][j] * inv;
  }
}

// ---------------- gate w = softmax([n,ctx] @ Wp + bp) in f64 ----------------
__global__ __launch_bounds__(256) void wgate_kernel(const double* __restrict__ n64,
                                                    const double* __restrict__ ctx64,
                                                    const float* __restrict__ Wp,
                                                    const float* __restrict__ bp,
                                                    double* __restrict__ w64) {
  const int t = blockIdx.x, tid = threadIdx.x;
  double l0 = 0.0, l1 = 0.0;
  for (int d = tid; d < CD; d += 256) {
    const double nd = n64[(size_t)t * CD + d];
    const double cd = ctx64[(size_t)t * CD + d];
    l0 += nd * (double)Wp[d * 2] + cd * (double)Wp[(CD + d) * 2];
    l1 += nd * (double)Wp[d * 2 + 1] + cd * (double)Wp[(CD + d) * 2 + 1];
  }
  for (int o = 32; o > 0; o >>= 1) { l0 += __shfl_down(l0, o); l1 += __shfl_down(l1, o); }
  __shared__ double sh[8];
  if ((tid & 63) == 0) { sh[tid >> 6] = l0; sh[4 + (tid >> 6)] = l1; }
  __syncthreads();
  if (tid == 0) {
    const double a = sh[0] + sh[1] + sh[2] + sh[3] + (double)bp[0];
    const double b = sh[4] + sh[5] + sh[6] + sh[7] + (double)bp[1];
    const double m = fmax(a, b);
    const double e0 = fexp64(a - m), e1 = fexp64(b - m);
    w64[t * 2] = e0 / (e0 + e1);
    w64[t * 2 + 1] = e1 / (e0 + e1);
  }
}

// ---------------- m = w0*n + w1*ctx (in place) + f32 copy ----------------
__global__ __launch_bounds__(256) void mcomb_kernel(double* __restrict__ n64,
                                                    const double* __restrict__ ctx64,
                                                    const double* __restrict__ w64,
                                                    float* __restrict__ m32) {
  const int t = blockIdx.x, tid = threadIdx.x;
  const double w0 = w64[t * 2], w1 = w64[t * 2 + 1];
  const size_t base = (size_t)t * CD + tid * 4;
#pragma unroll
  for (int u = 0; u < 4; ++u) {
    const double m = w0 * n64[base + u] + w1 * ctx64[base + u];
    n64[base + u] = m;
    m32[base + u] = (float)m;
  }
}

// ---------------- per-token: f32 prescreen (registers) + f64 rescore + exact top-16 ----------------
__global__ __launch_bounds__(256) void topk2_kernel(const float* __restrict__ scf, int t0,
                                                    const double* __restrict__ m64,
                                                    const double* __restrict__ neur64,
                                                    int* __restrict__ idxo,
                                                    float* __restrict__ twf) {
  const int tl = blockIdx.x, t = t0 + tl, tid = threadIdx.x;
  const int lane = tid & 63, wave = tid >> 6;
  __shared__ double mrow[CD];
  __shared__ float wmv[4];
  __shared__ int wiv[4];
  __shared__ float gbv;
  __shared__ int gbi;
  __shared__ int cand[NCAND];
  __shared__ double exact[NCAND];
  float v[CN / 256];  // this thread's 8 strided scores, register-resident
#pragma unroll
  for (int u = 0; u < CN / 256; ++u) v[u] = scf[(size_t)tl * CN + u * 256 + tid];
  for (int u = 0; u < CD / 256; ++u) mrow[u * 256 + tid] = m64[(size_t)t * CD + u * 256 + tid];
  __syncthreads();
  for (int r = 0; r < NCAND; ++r) {
    float best = -INFINITY;
    int bi = 1 << 30;
#pragma unroll
    for (int u = 0; u < CN / 256; ++u) {
      const int j = u * 256 + tid;
      const float val = v[u];
      if (val > best || (val == best && j < bi)) { best = val; bi = j; }
    }
    for (int o = 32; o > 0; o >>= 1) {
      const float ov = __shfl_down(best, o);
      const int oi = __shfl_down(bi, o);
      if (ov > best || (ov == best && oi < bi)) { best = ov; bi = oi; }
    }
    if (lane == 0) { wmv[wave] = best; wiv[wave] = bi; }
    __syncthreads();
    if (tid == 0) {
      float bb = wmv[0];
      int bj = wiv[0];
      for (int w2 = 1; w2 < 4; ++w2)
        if (wmv[w2] > bb || (wmv[w2] == bb && wiv[w2] < bj)) { bb = wmv[w2]; bj = wiv[w2]; }
      cand[r] = bj;
      gbi = bj;
    }
    __syncthreads();
    const int bj = gbi;
    if ((bj & 255) == tid) v[bj >> 8] = -INFINITY;  // winner clears its register
    __syncthreads();
  }
  {
    const int g = tid >> 3, l = tid & 7;
    const double* nr = neur64 + (size_t)cand[g] * CD;
    double p0 = 0.0, p1 = 0.0;
    for (int d = l; d < CD; d += 16) {
      p0 = fma(mrow[d], nr[d], p0);
      p1 = fma(mrow[d + 8], nr[d + 8], p1);
    }
    double p = p0 + p1;
    p += __shfl_down(p, 4);
    p += __shfl_down(p, 2);
    p += __shfl_down(p, 1);
    if (l == 0) exact[g] = p;
  }
  __syncthreads();
  if (tid == 0) {
    double topv[CK];
    int topi[CK];
    for (int r = 0; r < CK; ++r) {
      double bb = -INFINITY;
      int bc = -1;
      for (int c = 0; c < NCAND; ++c) {
        const double vv = exact[c];
        if (bc < 0 || vv > bb || (vv == bb && cand[c] < cand[bc])) { bb = vv; bc = c; }
      }
      topv[r] = bb; topi[r] = cand[bc];
      exact[bc] = -INFINITY;
    }
    const double m = topv[0];
    double e[CK], s = 0.0;
#pragma unroll
    for (int i = 0; i < CK; ++i) { e[i] = fexp64(topv[i] - m); s += e[i]; }
#pragma unroll
    for (int i = 0; i < CK; ++i) {
      twf[(size_t)t * CK + i] = (float)(e[i] / s);
      idxo[(size_t)t * CK + i] = topi[i];
    }
  }
}

// ---------------- final idx -> f32 copy into d_out (launched LAST) ----------------
__global__ __launch_bounds__(256) void idxout_kernel(const int* __restrict__ idxp,
                                                     float* __restrict__ out) {
  const int e = blockIdx.x * 256 + threadIdx.x;
  if (e < CT * CK) out[(size_t)CT * CD + (size_t)e] = (float)idxp[e];
}

// ---------------- per-batch sum of tw ----------------
__global__ __launch_bounds__(256) void bsum_kernel(const float* __restrict__ twf,
                                                   double* __restrict__ bs) {
  const int b = blockIdx.x, tid = threadIdx.x;
  double s = 0.0;
  for (int u = tid; u < CS * CK; u += 256) s += (double)twf[(size_t)b * CS * CK + u];
  for (int o = 32; o > 0; o >>= 1) s += __shfl_down(s, o);
  __shared__ double sh[4];
  if ((tid & 63) == 0) sh[tid >> 6] = s;
  __syncthreads();
  if (tid == 0) bs[b] = sh[0] + sh[1] + sh[2] + sh[3];
}

// ---------------- x1 = x + sum_k tw*neuron[idx]; token_sig = sum ----------------
__global__ __launch_bounds__(256) void x1_kernel(const float* __restrict__ x,
                                                 const int* __restrict__ idxp,
                                                 const float* __restrict__ twf,
                                                 const float* __restrict__ neur32,
                                                 float* __restrict__ x1,
                                                 float* __restrict__ tsig) {
  const int t = blockIdx.x, tid = threadIdx.x;
  __shared__ int si[CK];
  __shared__ float sw[CK];
  if (tid < CK) {
    int v = idxp[(size_t)t * CK + tid];
    si[tid] = (v >= 0 && v < CN) ? v : 0;
    sw[tid] = twf[(size_t)t * CK + tid];
  }
  __syncthreads();
  const int d0 = tid * 4;
  float4 acc = {0.f, 0.f, 0.f, 0.f};
#pragma unroll
  for (int kk = 0; kk < CK; ++kk) {
    const float4 nv = *reinterpret_cast<const float4*>(neur32 + (size_t)si[kk] * CD + d0);
    const float w = sw[kk];
    acc.x = fmaf(w, nv.x, acc.x); acc.y = fmaf(w, nv.y, acc.y);
    acc.z = fmaf(w, nv.z, acc.z); acc.w = fmaf(w, nv.w, acc.w);
  }
  const float4 xv = *reinterpret_cast<const float4*>(x + (size_t)t * CD + d0);
  *reinterpret_cast<float4*>(tsig + (size_t)t * CD + d0) = acc;
  float4 ov = {xv.x + acc.x, xv.y + acc.y, xv.z + acc.z, xv.w + acc.w};
  *reinterpret_cast<float4*>(x1 + (size_t)t * CD + d0) = ov;
}

// ---------------- sA/sB partials: grid (CB, 32) ----------------
__global__ __launch_bounds__(256) void sab_part_kernel(const int* __restrict__ idxp,
                                                       const float* __restrict__ twf,
                                                       const float* __restrict__ coefA,
                                                       const float* __restrict__ coefB,
                                                       double* __restrict__ pA,
                                                       double* __restrict__ pB) {
  const int b = blockIdx.x, pc = blockIdx.y, tid = threadIdx.x;
  const int i = tid & 31, g = tid >> 5;
  const size_t base = (size_t)b * CS * CK + (size_t)pc * 512;
  double aA = 0.0, aB = 0.0;
  for (int e = g; e < 512; e += 8) {
    const double w = (double)twf[base + e];
    int id = idxp[base + e];
    id = (id >= 0 && id < CN) ? id : 0;
    aA += w * (double)coefA[id * CNB + i];
    aB += w * (double)coefB[id * CNB + i];
  }
  __shared__ double rA[8][32], rB[8][32];
  rA[g][i] = aA; rB[g][i] = aB;
  __syncthreads();
  if (tid < 32) {
    double ta = 0.0, tb = 0.0;
#pragma unroll
    for (int g2 = 0; g2 < 8; ++g2) { ta += rA[g2][tid]; tb += rB[g2][tid]; }
    pA[((size_t)b * 32 + pc) * 32 + tid] = ta;
    pB[((size_t)b * 32 + pc) * 32 + tid] = tb;
  }
}

__global__ __launch_bounds__(256) void sab_final_kernel(const double* __restrict__ pA,
                                                        const double* __restrict__ pB,
                                                        const double* __restrict__ bs,
                                                        float* __restrict__ sA,
                                                        float* __restrict__ sB) {
  const int tid = threadIdx.x;
  const int b = tid >> 5, i = tid & 31;
  double ta = 0.0, tb = 0.0;
  for (int p = 0; p < 32; ++p) {
    ta += pA[((size_t)b * 32 + p) * 32 + i];
    tb += pB[((size_t)b * 32 + p) * 32 + i];
  }
  const double inv = 1.0 / (bs[b] + 1e-8);
  sA[b * CNB + i] = (float)(ta * inv);
  sB[b * CNB + i] = (float)(tb * inv);
}

// ---------------- A[b,:] = sum_i s[b,i]*basis[i,:] ----------------
__global__ __launch_bounds__(256) void amat_kernel(const float* __restrict__ sA,
                                                   const float* __restrict__ basis,
                                                   float* __restrict__ Am, int inner) {
  const int dr = blockIdx.x * 256 + threadIdx.x;
  __shared__ float ssa[CB * CNB];
  if (threadIdx.x < CB * CNB) ssa[threadIdx.x] = sA[threadIdx.x];
  __syncthreads();
  float acc[CB] = {};
  for (int i = 0; i < CNB; ++i) {
    const float bv = basis[(size_t)i * inner + dr];
#pragma unroll
    for (int b = 0; b < CB; ++b) acc[b] = fmaf(ssa[b * CNB + i], bv, acc[b]);
  }
#pragma unroll
  for (int b = 0; b < CB; ++b) Am[(size_t)b * inner + dr] = acc[b];
}

// ---------------- transpose + f32->bf16: WT[n][k] = bf16(W[k][n]) ----------------
__global__ __launch_bounds__(256) void transp_bf16_kernel(const float* __restrict__ W,
                                                          unsigned short* __restrict__ WT,
                                                          int K, int N) {
  const int k0 = blockIdx.x * 32, n0 = blockIdx.y * 32;
  __shared__ float t[32][33];
  const int tid = threadIdx.x;
  const int r = tid >> 3, c4 = (tid & 7) * 4;
  const float4 v = *reinterpret_cast<const float4*>(W + (size_t)(k0 + r) * N + n0 + c4);
  t[r][c4] = v.x; t[r][c4 + 1] = v.y; t[r][c4 + 2] = v.z; t[r][c4 + 3] = v.w;
  __syncthreads();
  unsigned short* op = WT + (size_t)(n0 + r) * K + k0 + c4;
  op[0] = f2bf(t[c4][r]); op[1] = f2bf(t[c4 + 1][r]);
  op[2] = f2bf(t[c4 + 2][r]); op[3] = f2bf(t[c4 + 3][r]);
}

// ---------------- bf16 MFMA GEMM: A f32 [M][K], BT bf16 [N][K] ----------------
// EPI: 0 -> Op = acc; 3 -> Op = relu(acc+bias); 4 -> Op += 0.1*(acc+bias); 5 -> ofin = aux+acc+bias
template <int EPI>
__global__ __launch_bounds__(256) void gemm_bf16_kernel(
    const float* __restrict__ A, const unsigned short* __restrict__ BT,
    float* __restrict__ Op, const float* __restrict__ bias,
    const float* __restrict__ aux, float* __restrict__ ofin, int Kd, int Nc) {
  const int bn = blockIdx.x * 64, bm = blockIdx.y * 64;
  const int tid = threadIdx.x, lane = tid & 63, wid = tid >> 6;
  const int wm = wid >> 1, wn = wid & 1, l15 = lane & 15, l4 = lane >> 4;
  __shared__ unsigned short as[64][40];
  __shared__ unsigned short bs[64][40];
  f32x4v acc[2][2] = {};
  const int sr = tid >> 2, sk = (tid & 3) * 8;
  for (int k0 = 0; k0 < Kd; k0 += 32) {
    const float4* ap = reinterpret_cast<const float4*>(A + (size_t)(bm + sr) * Kd + k0 + sk);
    const float4 a0 = ap[0], a1 = ap[1];
    as[sr][sk + 0] = f2bf(a0.x); as[sr][sk + 1] = f2bf(a0.y);
    as[sr][sk + 2] = f2bf(a0.z); as[sr][sk + 3] = f2bf(a0.w);
    as[sr][sk + 4] = f2bf(a1.x); as[sr][sk + 5] = f2bf(a1.y);
    as[sr][sk + 6] = f2bf(a1.z); as[sr][sk + 7] = f2bf(a1.w);
    *reinterpret_cast<uint4*>(&bs[sr][sk]) =
        *reinterpret_cast<const uint4*>(BT + (size_t)(bn + sr) * Kd + k0 + sk);
    __syncthreads();
    const short8 af0 = *reinterpret_cast<const short8*>(&as[wm * 32 + l15][l4 * 8]);
    const short8 af1 = *reinterpret_cast<const short8*>(&as[wm * 32 + 16 + l15][l4 * 8]);
    const short8 bf0 = *reinterpret_cast<const short8*>(&bs[wn * 32 + l15][l4 * 8]);
    const short8 bf1 = *reinterpret_cast<const short8*>(&bs[wn * 32 + 16 + l15][l4 * 8]);
    acc[0][0] = __builtin_amdgcn_mfma_f32_16x16x32_bf16(af0, bf0, acc[0][0], 0, 0, 0);
    acc[0][1] = __builtin_amdgcn_mfma_f32_16x16x32_bf16(af0, bf1, acc[0][1], 0, 0, 0);
    acc[1][0] = __builtin_amdgcn_mfma_f32_16x16x32_bf16(af1, bf0, acc[1][0], 0, 0, 0);
    acc[1][1] = __builtin_amdgcn_mfma_f32_16x16x32_bf16(af1, bf1, acc[1][1], 0, 0, 0);
    __syncthreads();
  }
#pragma unroll
  for (int i = 0; i < 2; ++i)
#pragma unroll
    for (int j = 0; j < 2; ++j)
#pragma unroll
      for (int b = 0; b < 4; ++b) {
        const int row = bm + wm * 32 + i * 16 + l4 * 4 + b;
        const int col = bn + wn * 32 + j * 16 + l15;
        const float v = acc[i][j][b];
        if (EPI == 0) {
          Op[(size_t)row * Nc + col] = v;
        } else if (EPI == 3) {
          const float vv = v + bias[col];
          Op[(size_t)row * Nc + col] = vv > 0.f ? vv : 0.f;
        } else if (EPI == 4) {
          Op[(size_t)row * Nc + col] += 0.1f * (v + bias[col]);
        } else {
          ofin[(size_t)row * Nc + col] = aux[(size_t)row * Nc + col] + v + bias[col];
        }
      }
}

// ---------------- generic f32 tiled GEMM (EPI 0 plain, 2 gelu) ----------------
template <int EPI>
__global__ __launch_bounds__(256) void gemm_kernel(
    const float* __restrict__ Ap, const float* __restrict__ Bp,
    float* __restrict__ Op, int M, int Kd, int Nc, size_t sA, size_t sB, size_t sO) {
  const int bn = blockIdx.x * 64, bm = blockIdx.y * 64, bz = blockIdx.z;
  const int tid = threadIdx.x, tx = tid & 15, ty = tid >> 4;
  const float* Af = Ap + (size_t)bz * sA;
  const float* Bb = Bp + (size_t)bz * sB;
  __shared__ float as[64][17];
  __shared__ float bs[16][64];
  float acc[4][4] = {};
  const int lr = tid >> 2, lk = (tid & 3) * 4;
  const int br = tid >> 4, bc = (tid & 15) * 4;
  for (int k0 = 0; k0 < Kd; k0 += 16) {
    const float4 a4 = *reinterpret_cast<const float4*>(Af + (size_t)(bm + lr) * Kd + k0 + lk);
    as[lr][lk + 0] = a4.x; as[lr][lk + 1] = a4.y; as[lr][lk + 2] = a4.z; as[lr][lk + 3] = a4.w;
    const float4 b4 = *reinterpret_cast<const float4*>(Bb + (size_t)(k0 + br) * Nc + bn + bc);
    *reinterpret_cast<float4*>(&bs[br][bc]) = b4;
    __syncthreads();
#pragma unroll
    for (int kk = 0; kk < 16; ++kk) {
      float a[4], b[4];
#pragma unroll
      for (int i = 0; i < 4; ++i) a[i] = as[ty * 4 + i][kk];
#pragma unroll
      for (int j = 0; j < 4; ++j) b[j] = bs[kk][tx * 4 + j];
#pragma unroll
      for (int i = 0; i < 4; ++i)
#pragma unroll
        for (int j = 0; j < 4; ++j) acc[i][j] = fmaf(a[i], b[j], acc[i][j]);
    }
    __syncthreads();
  }
#pragma unroll
  for (int i = 0; i < 4; ++i) {
    const int row = bm + ty * 4 + i;
#pragma unroll
    for (int j = 0; j < 4; ++j) {
      const int col = bn + tx * 4 + j;
      const float vacc = acc[i][j];
      if (EPI == 0) {
        Op[(size_t)bz * sO + (size_t)row * Nc + col] = vacc;
      } else if (EPI == 2) {
        Op[(size_t)bz * sO + (size_t)row * Nc + col] =
            0.5f * vacc * (1.0f + erff(vacc * 0.70710678118654752f));
      }
    }
  }
}

// =======================================================================
extern "C" void kernel_launch(void* const* d_in, const int* in_sizes, int n_in,
                              void* d_out, int out_size, void* d_ws, size_t ws_size,
                              hipStream_t stream) {
  const float* x = (const float*)d_in[0];
  const float* g1 = (const float*)d_in[1];
  const float* be1 = (const float*)d_in[2];
  const float* g2 = (const float*)d_in[3];
  const float* be2 = (const float*)d_in[4];
  const float* Wq = (const float*)d_in[5];
  const float* bq = (const float*)d_in[6];
  const float* Wk = (const float*)d_in[7];
  const float* bk = (const float*)d_in[8];
  const float* Wv = (const float*)d_in[9];
  const float* bv = (const float*)d_in[10];
  const float* Wp = (const float*)d_in[11];
  const float* bp = (const float*)d_in[12];
  const float* nA = (const float*)d_in[13];
  const float* nB = (const float*)d_in[14];
  const float* basisA = (const float*)d_in[15];
  const float* basisB = (const float*)d_in[16];
  const float* coefA = (const float*)d_in[17];
  const float* coefB = (const float*)d_in[18];
  const float* Wr1 = (const float*)d_in[19];
  const float* br1 = (const float*)d_in[20];
  const float* Wr2 = (const float*)d_in[21];
  const float* br2 = (const float*)d_in[22];
  const float* Wd = (const float*)d_in[23];
  const float* bd = (const float*)d_in[24];
  float* out = (float*)d_out;

  // --- workspace overlay (224 MiB) ---
  const size_t MB = 1ull << 20;
  if (ws_size < 224 * MB) return;
  char* W = (char*)d_ws;
  double* n64 = (double*)(W + 0 * MB);
  double* ctx64 = (double*)(W + 64 * MB);
  double* neur64 = (double*)(W + 128 * MB);
  double* qkv2 = (double*)(W + 144 * MB);   // 50.3 MB (HP=4), dead after attn loop
  float* scsl = (float*)(W + 144 * MB);
  int* idxp = (int*)(W + 152 * MB);
  float* twf = (float*)(W + 152 * MB + 512 * 1024);
  double* w64 = (double*)(W + 153 * MB);
  double* bsum = (double*)(W + 153 * MB + 256 * 1024);
  float* sA = (float*)(W + 153 * MB + 256 * 1024 + 4096);
  float* sB = (float*)(W + 153 * MB + 256 * 1024 + 8192);
  double* pA = (double*)(W + 153 * MB + 512 * 1024);
  double* pB = (double*)(W + 153 * MB + 512 * 1024 + 64 * 1024);
  float* n2b = (float*)(W + 0 * MB);
  float* hbuf = (float*)(W + 0 * MB);
  float* tsig = (float*)(W + 64 * MB);
  float* Bm = (float*)(W + 156 * MB);
  float* Gb = (float*)(W + 164 * MB);
  float* Am = (float*)(W + 166 * MB);
  unsigned short* Wr1T = (unsigned short*)(W + 168 * MB);
  unsigned short* Wr2T = (unsigned short*)(W + 170 * MB);
  unsigned short* WdT = (unsigned short*)(W + 172 * MB);
  float* m32 = (float*)(W + 180 * MB);
  float* x1b = (float*)(W + 180 * MB);
  float* neur32 = (float*)(W + 212 * MB);
  float* hf1 = (float*)(W + 212 * MB);
  unsigned short* nbf = (unsigned short*)(W + 220 * MB);

  // ---- Phase A: f64 router ----
  ln_kernel<double><<<CT, 256, 0, stream>>>(x, g1, be1, n64);
  neurons_kernel<<<dim3(CD / 256, CN), 256, 0, stream>>>(nA, nB, neur64, neur32, nbf);
  for (int hp = 0; hp < CD / CDH / HP; ++hp) {
    const int h0 = hp * HP;
    qkv64_z<<<dim3(HP, CT / 64), 768, 0, stream>>>(n64, Wq, Wk, Wv, bq, bk, bv, h0, qkv2);
    attn64_v4<<<dim3(CS / 64, CB, HP), 512, 0, stream>>>(qkv2, h0, ctx64);
  }
  wgate_kernel<<<CT, 256, 0, stream>>>(n64, ctx64, Wp, bp, w64);
  mcomb_kernel<<<CT, 256, 0, stream>>>(n64, ctx64, w64, m32);
  // weight prep (regions [168,180) are free only after the attn loop)
  transp_bf16_kernel<<<dim3(CFF / 32, CD / 32), 256, 0, stream>>>(Wd, WdT, CFF, CD);
  transp_bf16_kernel<<<dim3(CRH / 32, CFF / 32), 256, 0, stream>>>(Wr2, Wr2T, CRH, CFF);
  transp_bf16_kernel<<<dim3(CD / 32, CRH / 32), 256, 0, stream>>>(Wr1, Wr1T, CD, CRH);
  for (int t0 = 0; t0 < CT; t0 += SLICE) {
    gemm_bf16_kernel<0><<<dim3(CN / 64, SLICE / 64), 256, 0, stream>>>(
        m32 + (size_t)t0 * CD, nbf, scsl, nullptr, nullptr, nullptr, CD, CN);
    topk2_kernel<<<SLICE, 256, 0, stream>>>(scsl, t0, n64, neur64, idxp, twf);
  }

  // ---- Phase B: FFN ----
  bsum_kernel<<<CB, 256, 0, stream>>>(twf, bsum);
  x1_kernel<<<CT, 256, 0, stream>>>(x, idxp, twf, neur32, x1b, tsig);
  ln_kernel<float><<<CT, 256, 0, stream>>>(x1b, g2, be2, n2b);
  sab_part_kernel<<<dim3(CB, 32), 256, 0, stream>>>(idxp, twf, coefA, coefB, pA, pB);
  sab_final_kernel<<<1, 256, 0, stream>>>(pA, pB, bsum, sA, sB);
  amat_kernel<<<(CD * CBR) / 256, 256, 0, stream>>>(sA, basisA, Am, CD * CBR);
  amat_kernel<<<(CBR * CFF) / 256, 256, 0, stream>>>(sB, basisB, Bm, CBR * CFF);
  gemm_kernel<0><<<dim3(CBR / 64, CS / 64, CB), 256, 0, stream>>>(
      n2b, Am, Gb, CS, CD, CBR, (size_t)CS * CD, (size_t)CD * CBR, (size_t)CS * CBR);
  gemm_bf16_kernel<3><<<dim3(CRH / 64, CT / 64), 256, 0, stream>>>(
      tsig, Wr1T, hf1, br1, nullptr, nullptr, CD, CRH);
  gemm_kernel<2><<<dim3(CFF / 64, CS / 64, CB), 256, 0, stream>>>(
      Gb, Bm, hbuf, CS, CBR, CFF, (size_t)CS * CBR, (size_t)CBR * CFF, (size_t)CS * CFF);
  gemm_bf16_kernel<4><<<dim3(CFF / 64, CT / 64), 256, 0, stream>>>(
      hf1, Wr2T, hbuf, br2, nullptr, nullptr, CRH, CFF);
  gemm_bf16_kernel<5><<<dim3(CD / 64, CT / 64), 256, 0, stream>>>(
      hbuf, WdT, nullptr, bd, x1b, out, CFF, CD);
  idxout_kernel<<<(CT * CK + 255) / 256, 256, 0, stream>>>(idxp, out);
}

// Round 15
// 4597.881 us; speedup vs baseline: 1.1505x; 1.1505x over previous
//
#include <hip/hip_runtime.h>
#include <hip/hip_bf16.h>
#include <math.h>

namespace {
constexpr int CB = 8;      // batch
constexpr int CS = 1024;   // seq
constexpr int CD = 1024;   // d_model
constexpr int CDH = 64;    // head dim
constexpr int CK = 16;     // neuron_k
constexpr int CN = 2048;   // n_neurons
constexpr int CNB = 32;    // n_basis
constexpr int CBR = 64;    // basis_rank
constexpr int CFF = 4096;  // d_ff
constexpr int CRH = 256;   // token residual hidden
constexpr int CT = CB * CS;  // 8192 tokens
constexpr int HP = 4;        // heads per outer iteration
constexpr int SLICE = 1024;  // tokens per scores/topk slice
constexpr int NCAND = 32;    // prescreen candidates
}

using f32x4v = __attribute__((ext_vector_type(4))) float;
using short8 = __attribute__((ext_vector_type(8))) short;

__device__ __forceinline__ unsigned short f2bf(float f) {
  unsigned u = __builtin_bit_cast(unsigned, f);
  u = (u + 0x7FFFu + ((u >> 16) & 1u)) >> 16;
  return (unsigned short)u;
}

// ---- fast double exp: Cody-Waite + degree-12 Taylor, rel err ~2e-16 ----
__device__ __forceinline__ double fexp64(double x) {
  x = fmin(fmax(x, -700.0), 700.0);
  const double kd = rint(x * 1.4426950408889634074);
  double r = fma(-kd, 6.93147180369123816490e-01, x);
  r = fma(-kd, 1.90821492927058770002e-10, r);
  double p = 2.087675698786810e-9;
  p = fma(p, r, 2.505210838544172e-8);
  p = fma(p, r, 2.755731922398589e-7);
  p = fma(p, r, 2.755731922398589e-6);
  p = fma(p, r, 2.480158730158730e-5);
  p = fma(p, r, 1.984126984126984e-4);
  p = fma(p, r, 1.388888888888889e-3);
  p = fma(p, r, 8.333333333333333e-3);
  p = fma(p, r, 4.166666666666666e-2);
  p = fma(p, r, 1.666666666666667e-1);
  p = fma(p, r, 0.5);
  p = fma(p, r, 1.0);
  p = fma(p, r, 1.0);
  const long long ki = (long long)kd;
  return p * __longlong_as_double((ki + 1023LL) << 52);
}

// ---------------- LayerNorm ----------------
template <typename TOUT>
__global__ __launch_bounds__(256) void ln_kernel(const float* __restrict__ x,
                                                 const float* __restrict__ g,
                                                 const float* __restrict__ be,
                                                 TOUT* __restrict__ out) {
  const int t = blockIdx.x, tid = threadIdx.x;
  const float4 v = reinterpret_cast<const float4*>(x + (size_t)t * CD)[tid];
  double s = (double)v.x + (double)v.y + (double)v.z + (double)v.w;
  double ss = (double)v.x * v.x + (double)v.y * v.y + (double)v.z * v.z + (double)v.w * v.w;
  for (int o = 32; o > 0; o >>= 1) { s += __shfl_down(s, o); ss += __shfl_down(ss, o); }
  __shared__ double sh[8];
  if ((tid & 63) == 0) { sh[tid >> 6] = s; sh[4 + (tid >> 6)] = ss; }
  __syncthreads();
  const double st = sh[0] + sh[1] + sh[2] + sh[3];
  const double sq = sh[4] + sh[5] + sh[6] + sh[7];
  const double mean = st * (1.0 / CD);
  const double var = sq * (1.0 / CD) - mean * mean;
  const double rstd = 1.0 / sqrt(var + 1e-5);
  const int d0 = tid * 4;
  TOUT* o4 = out + (size_t)t * CD + d0;
  o4[0] = (TOUT)((((double)v.x) - mean) * rstd * (double)g[d0 + 0] + (double)be[d0 + 0]);
  o4[1] = (TOUT)((((double)v.y) - mean) * rstd * (double)g[d0 + 1] + (double)be[d0 + 1]);
  o4[2] = (TOUT)((((double)v.z) - mean) * rstd * (double)g[d0 + 2] + (double)be[d0 + 2]);
  o4[3] = (TOUT)((((double)v.w) - mean) * rstd * (double)g[d0 + 3] + (double)be[d0 + 3]);
}

// ---------------- neurons = nA @ nB (f64) + f32 + bf16 copies ----------------
__global__ __launch_bounds__(256) void neurons_kernel(const float* __restrict__ nA,
                                                      const float* __restrict__ nB,
                                                      double* __restrict__ n64,
                                                      float* __restrict__ n32,
                                                      unsigned short* __restrict__ nbf) {
  const int j = blockIdx.y;
  const int d = blockIdx.x * 256 + threadIdx.x;
  double acc = 0.0;
#pragma unroll
  for (int r = 0; r < 32; ++r)
    acc += (double)nA[j * 32 + r] * (double)nB[r * CD + d];
  n64[(size_t)j * CD + d] = acc;
  const float f = (float)acc;
  n32[(size_t)j * CD + d] = f;
  nbf[(size_t)j * CD + d] = f2bf(f);
}

// ---------------- fused f64 QKV gemm, z-specialized waves (r10 measured-best) ----------------
// grid (HP, CT/64), 768 threads (12 waves): waves 0-3 -> Q, 4-7 -> K, 8-11 -> V.
__global__ __launch_bounds__(768) void qkv64_z(
    const double* __restrict__ n64, const float* __restrict__ Wq,
    const float* __restrict__ Wk, const float* __restrict__ Wv,
    const float* __restrict__ bq, const float* __restrict__ bk,
    const float* __restrict__ bv, int h0, double* __restrict__ qkv2) {
  const int hh = blockIdx.x, bm = blockIdx.y * 64;
  const int cbase = (h0 + hh) * 64;
  const int tid = threadIdx.x;
  const int wv = tid >> 6, lane = tid & 63;
  const int z = wv >> 2, w2 = wv & 3;
  const int tx = lane & 15, ty = w2 * 4 + (lane >> 4);  // ty in 0..15
  __shared__ double aT[16][65];      // [k][m] f64 (broadcast reads)
  __shared__ float bsf[3][16][64];   // [z][k][n] raw f32
  double acc[4][4] = {};
  // staging: A by first 256 threads; B by all 768 (one z each)
  const int lr = (tid & 255) >> 2, lk = (tid & 3) * 4;
  const int zz = tid >> 8, t2 = tid & 255, br = t2 >> 4, bc = (t2 & 15) * 4;
  const float* Wz = (zz == 0) ? Wq : ((zz == 1) ? Wk : Wv);
  for (int k0 = 0; k0 < CD; k0 += 16) {
    if (tid < 256) {
      const double2* p = reinterpret_cast<const double2*>(n64 + (size_t)(bm + lr) * CD + k0 + lk);
      double2 a0 = p[0], a1 = p[1];
      aT[lk + 0][lr] = a0.x; aT[lk + 1][lr] = a0.y;
      aT[lk + 2][lr] = a1.x; aT[lk + 3][lr] = a1.y;
    }
    *reinterpret_cast<float4*>(&bsf[zz][br][bc]) =
        *reinterpret_cast<const float4*>(Wz + (size_t)(k0 + br) * CD + cbase + bc);
    __syncthreads();
#pragma unroll
    for (int kk = 0; kk < 16; ++kk) {
      double a[4];
#pragma unroll
      for (int i = 0; i < 4; ++i) a[i] = aT[kk][ty * 4 + i];
      const float4 bf = *reinterpret_cast<const float4*>(&bsf[z][kk][tx * 4]);
      const double b0 = (double)bf.x, b1 = (double)bf.y;
      const double b2 = (double)bf.z, b3 = (double)bf.w;
#pragma unroll
      for (int i = 0; i < 4; ++i) {
        acc[i][0] = fma(a[i], b0, acc[i][0]);
        acc[i][1] = fma(a[i], b1, acc[i][1]);
        acc[i][2] = fma(a[i], b2, acc[i][2]);
        acc[i][3] = fma(a[i], b3, acc[i][3]);
      }
    }
    __syncthreads();
  }
  const float* bb = (z == 0) ? bq : ((z == 1) ? bk : bv);
  double* outp = qkv2 + (size_t)(z * HP + hh) * CT * CDH;
#pragma unroll
  for (int i = 0; i < 4; ++i)
#pragma unroll
    for (int j = 0; j < 4; ++j)
      outp[(size_t)(bm + ty * 4 + i) * CDH + tx * 4 + j] =
          acc[i][j] + (double)bb[cbase + tx * 4 + j];
}

// ---------------- f64 attention v2 (r10 measured-best, verbatim) ----------------
__global__ __launch_bounds__(256) void attn64_v2(const double* __restrict__ qkv2,
                                                 int h0, double* __restrict__ ctx64) {
  const int qt = blockIdx.x, b = blockIdx.y, hh = blockIdx.z;
  const int tid = threadIdx.x;
  const int tq = tid >> 4, tk = tid & 15;
  const double* qp = qkv2 + ((size_t)(0 * HP + hh) * CT + (size_t)b * CS) * CDH;
  const double* kp = qkv2 + ((size_t)(1 * HP + hh) * CT + (size_t)b * CS) * CDH;
  const double* vp = qkv2 + ((size_t)(2 * HP + hh) * CT + (size_t)b * CS) * CDH;
  __shared__ double qT[64][66];
  __shared__ double kps[64][34];
  __shared__ double vsd[32][66];
  __shared__ double rowl[64];
  for (int it = 0; it < 16; ++it) {
    const int idx = it * 256 + tid, r = idx >> 6, d = idx & 63;
    qT[d][r] = qp[(size_t)(qt * 64 + r) * CDH + d];
  }
  if (tid < 64) rowl[tid] = 0.0;
  double od[4][4] = {};
  const int q0 = tq * 4, k0c = tk * 2, d0 = tk * 4;
  for (int kt = 0; kt < CS / 32; ++kt) {
    __syncthreads();
    for (int it = 0; it < 8; ++it) {
      const int idx = it * 256 + tid, kc = idx >> 6, d = idx & 63;
      kps[d][kc] = kp[(size_t)(kt * 32 + kc) * CDH + d];
      vsd[kc][d] = vp[(size_t)(kt * 32 + kc) * CDH + d];
    }
    __syncthreads();
    double s[4][2] = {};
#pragma unroll 4
    for (int c = 0; c < 64; ++c) {
      const double a0 = qT[c][q0], a1 = qT[c][q0 + 1];
      const double a2 = qT[c][q0 + 2], a3 = qT[c][q0 + 3];
      const double b0 = kps[c][k0c], b1 = kps[c][k0c + 1];
      s[0][0] = fma(a0, b0, s[0][0]); s[0][1] = fma(a0, b1, s[0][1]);
      s[1][0] = fma(a1, b0, s[1][0]); s[1][1] = fma(a1, b1, s[1][1]);
      s[2][0] = fma(a2, b0, s[2][0]); s[2][1] = fma(a2, b1, s[2][1]);
      s[3][0] = fma(a3, b0, s[3][0]); s[3][1] = fma(a3, b1, s[3][1]);
    }
    __syncthreads();
    double pr[4][2], rsum[4];
#pragma unroll
    for (int i = 0; i < 4; ++i) {
      pr[i][0] = fexp64(s[i][0] * 0.125);
      pr[i][1] = fexp64(s[i][1] * 0.125);
      rsum[i] = pr[i][0] + pr[i][1];
    }
#pragma unroll
    for (int off = 1; off <= 8; off <<= 1)
#pragma unroll
      for (int i = 0; i < 4; ++i) rsum[i] += __shfl_xor(rsum[i], off);
    if (tk == 0) {
#pragma unroll
      for (int i = 0; i < 4; ++i) rowl[q0 + i] += rsum[i];
    }
#pragma unroll
    for (int i = 0; i < 4; ++i) {
      kps[q0 + i][k0c] = pr[i][0];
      kps[q0 + i][k0c + 1] = pr[i][1];
    }
    __syncthreads();
#pragma unroll 4
    for (int kc = 0; kc < 32; ++kc) {
      const double pa0 = kps[q0][kc], pa1 = kps[q0 + 1][kc];
      const double pa2 = kps[q0 + 2][kc], pa3 = kps[q0 + 3][kc];
      const double v0 = vsd[kc][d0], v1 = vsd[kc][d0 + 1];
      const double v2 = vsd[kc][d0 + 2], v3 = vsd[kc][d0 + 3];
      od[0][0] = fma(pa0, v0, od[0][0]); od[0][1] = fma(pa0, v1, od[0][1]);
      od[0][2] = fma(pa0, v2, od[0][2]); od[0][3] = fma(pa0, v3, od[0][3]);
      od[1][0] = fma(pa1, v0, od[1][0]); od[1][1] = fma(pa1, v1, od[1][1]);
      od[1][2] = fma(pa1, v2, od[1][2]); od[1][3] = fma(pa1, v3, od[1][3]);
      od[2][0] = fma(pa2, v0, od[2][0]); od[2][1] = fma(pa2, v1, od[2][1]);
      od[2][2] = fma(pa2, v2, od[2][2]); od[2][3] = fma(pa2, v3, od[2][3]);
      od[3][0] = fma(pa3, v0, od[3][0]); od[3][1] = fma(pa3, v1, od[3][1]);
      od[3][2] = fma(pa3, v2, od[3][2]); od[3][3] = fma(pa3, v3, od[3][3]);
    }
  }
  __syncthreads();
  double* cp = ctx64 + (size_t)b * CS * CD + (size_t)(h0 + hh) * CDH;
#pragma unroll
  for (int i = 0; i < 4; ++i) {
    const double inv = 1.0 / rowl[q0 + i];
    const size_t rbase = (size_t)(qt * 64 + q0 + i) * CD;
#pragma unroll
    for (int j = 0; j < 4; ++j) cp[rbase + d0 + j] = od[i][j] * inv;
  }
}

// ---------------- gate w = softmax([n,ctx] @ Wp + bp) in f64 ----------------
__global__ __launch_bounds__(256) void wgate_kernel(const double* __restrict__ n64,
                                                    const double* __restrict__ ctx64,
                                                    const float* __restrict__ Wp,
                                                    const float* __restrict__ bp,
                                                    double* __restrict__ w64) {
  const int t = blockIdx.x, tid = threadIdx.x;
  double l0 = 0.0, l1 = 0.0;
  for (int d = tid; d < CD; d += 256) {
    const double nd = n64[(size_t)t * CD + d];
    const double cd = ctx64[(size_t)t * CD + d];
    l0 += nd * (double)Wp[d * 2] + cd * (double)Wp[(CD + d) * 2];
    l1 += nd * (double)Wp[d * 2 + 1] + cd * (double)Wp[(CD + d) * 2 + 1];
  }
  for (int o = 32; o > 0; o >>= 1) { l0 += __shfl_down(l0, o); l1 += __shfl_down(l1, o); }
  __shared__ double sh[8];
  if ((tid & 63) == 0) { sh[tid >> 6] = l0; sh[4 + (tid >> 6)] = l1; }
  __syncthreads();
  if (tid == 0) {
    const double a = sh[0] + sh[1] + sh[2] + sh[3] + (double)bp[0];
    const double b = sh[4] + sh[5] + sh[6] + sh[7] + (double)bp[1];
    const double m = fmax(a, b);
    const double e0 = fexp64(a - m), e1 = fexp64(b - m);
    w64[t * 2] = e0 / (e0 + e1);
    w64[t * 2 + 1] = e1 / (e0 + e1);
  }
}

// ---------------- m = w0*n + w1*ctx (in place) + f32 copy ----------------
__global__ __launch_bounds__(256) void mcomb_kernel(double* __restrict__ n64,
                                                    const double* __restrict__ ctx64,
                                                    const double* __restrict__ w64,
                                                    float* __restrict__ m32) {
  const int t = blockIdx.x, tid = threadIdx.x;
  const double w0 = w64[t * 2], w1 = w64[t * 2 + 1];
  const size_t base = (size_t)t * CD + tid * 4;
#pragma unroll
  for (int u = 0; u < 4; ++u) {
    const double m = w0 * n64[base + u] + w1 * ctx64[base + u];
    n64[base + u] = m;
    m32[base + u] = (float)m;
  }
}

// ---------------- per-token: f32 prescreen top-32 + f64 rescore + exact top-16 ----------------
__global__ __launch_bounds__(256) void topk2_kernel(const float* __restrict__ scf, int t0,
                                                    const double* __restrict__ m64,
                                                    const double* __restrict__ neur64,
                                                    int* __restrict__ idxo,
                                                    float* __restrict__ twf) {
  const int tl = blockIdx.x, t = t0 + tl, tid = threadIdx.x;
  const int lane = tid & 63, wave = tid >> 6;
  __shared__ float sv[CN];
  __shared__ double mrow[CD];
  __shared__ float wmv[4];
  __shared__ int wiv[4];
  __shared__ int cand[NCAND];
  __shared__ double exact[NCAND];
  for (int u = 0; u < CN / 256; ++u) sv[u * 256 + tid] = scf[(size_t)tl * CN + u * 256 + tid];
  for (int u = 0; u < CD / 256; ++u) mrow[u * 256 + tid] = m64[(size_t)t * CD + u * 256 + tid];
  __syncthreads();
  for (int r = 0; r < NCAND; ++r) {
    float best = -INFINITY;
    int bi = 1 << 30;
    for (int u = 0; u < CN / 256; ++u) {
      const int j = u * 256 + tid;
      const float val = sv[j];
      if (val > best || (val == best && j < bi)) { best = val; bi = j; }
    }
    for (int o = 32; o > 0; o >>= 1) {
      const float ov = __shfl_down(best, o);
      const int oi = __shfl_down(bi, o);
      if (ov > best || (ov == best && oi < bi)) { best = ov; bi = oi; }
    }
    if (lane == 0) { wmv[wave] = best; wiv[wave] = bi; }
    __syncthreads();
    if (tid == 0) {
      float bb = wmv[0];
      int bj = wiv[0];
      for (int w2 = 1; w2 < 4; ++w2)
        if (wmv[w2] > bb || (wmv[w2] == bb && wiv[w2] < bj)) { bb = wmv[w2]; bj = wiv[w2]; }
      cand[r] = bj;
      sv[bj] = -INFINITY;
    }
    __syncthreads();
  }
  {
    const int g = tid >> 3, l = tid & 7;
    const double* nr = neur64 + (size_t)cand[g] * CD;
    double p0 = 0.0, p1 = 0.0;
    for (int d = l; d < CD; d += 16) {
      p0 = fma(mrow[d], nr[d], p0);
      p1 = fma(mrow[d + 8], nr[d + 8], p1);
    }
    double p = p0 + p1;
    p += __shfl_down(p, 4);
    p += __shfl_down(p, 2);
    p += __shfl_down(p, 1);
    if (l == 0) exact[g] = p;
  }
  __syncthreads();
  if (tid == 0) {
    double topv[CK];
    int topi[CK];
    for (int r = 0; r < CK; ++r) {
      double bb = -INFINITY;
      int bc = -1;
      for (int c = 0; c < NCAND; ++c) {
        const double v = exact[c];
        if (bc < 0 || v > bb || (v == bb && cand[c] < cand[bc])) { bb = v; bc = c; }
      }
      topv[r] = bb; topi[r] = cand[bc];
      exact[bc] = -INFINITY;
    }
    const double m = topv[0];
    double e[CK], s = 0.0;
#pragma unroll
    for (int i = 0; i < CK; ++i) { e[i] = fexp64(topv[i] - m); s += e[i]; }
#pragma unroll
    for (int i = 0; i < CK; ++i) {
      twf[(size_t)t * CK + i] = (float)(e[i] / s);
      idxo[(size_t)t * CK + i] = topi[i];
    }
  }
}

// ---------------- final idx -> f32 copy into d_out (launched LAST) ----------------
__global__ __launch_bounds__(256) void idxout_kernel(const int* __restrict__ idxp,
                                                     float* __restrict__ out) {
  const int e = blockIdx.x * 256 + threadIdx.x;
  if (e < CT * CK) out[(size_t)CT * CD + (size_t)e] = (float)idxp[e];
}

// ---------------- per-batch sum of tw ----------------
__global__ __launch_bounds__(256) void bsum_kernel(const float* __restrict__ twf,
                                                   double* __restrict__ bs) {
  const int b = blockIdx.x, tid = threadIdx.x;
  double s = 0.0;
  for (int u = tid; u < CS * CK; u += 256) s += (double)twf[(size_t)b * CS * CK + u];
  for (int o = 32; o > 0; o >>= 1) s += __shfl_down(s, o);
  __shared__ double sh[4];
  if ((tid & 63) == 0) sh[tid >> 6] = s;
  __syncthreads();
  if (tid == 0) bs[b] = sh[0] + sh[1] + sh[2] + sh[3];
}

// ---------------- x1 = x + sum_k tw*neuron[idx]; token_sig = sum ----------------
__global__ __launch_bounds__(256) void x1_kernel(const float* __restrict__ x,
                                                 const int* __restrict__ idxp,
                                                 const float* __restrict__ twf,
                                                 const float* __restrict__ neur32,
                                                 float* __restrict__ x1,
                                                 float* __restrict__ tsig) {
  const int t = blockIdx.x, tid = threadIdx.x;
  __shared__ int si[CK];
  __shared__ float sw[CK];
  if (tid < CK) {
    int v = idxp[(size_t)t * CK + tid];
    si[tid] = (v >= 0 && v < CN) ? v : 0;
    sw[tid] = twf[(size_t)t * CK + tid];
  }
  __syncthreads();
  const int d0 = tid * 4;
  float4 acc = {0.f, 0.f, 0.f, 0.f};
#pragma unroll
  for (int kk = 0; kk < CK; ++kk) {
    const float4 nv = *reinterpret_cast<const float4*>(neur32 + (size_t)si[kk] * CD + d0);
    const float w = sw[kk];
    acc.x = fmaf(w, nv.x, acc.x); acc.y = fmaf(w, nv.y, acc.y);
    acc.z = fmaf(w, nv.z, acc.z); acc.w = fmaf(w, nv.w, acc.w);
  }
  const float4 xv = *reinterpret_cast<const float4*>(x + (size_t)t * CD + d0);
  *reinterpret_cast<float4*>(tsig + (size_t)t * CD + d0) = acc;
  float4 ov = {xv.x + acc.x, xv.y + acc.y, xv.z + acc.z, xv.w + acc.w};
  *reinterpret_cast<float4*>(x1 + (size_t)t * CD + d0) = ov;
}

// ---------------- sA/sB partials: grid (CB, 32) ----------------
__global__ __launch_bounds__(256) void sab_part_kernel(const int* __restrict__ idxp,
                                                       const float* __restrict__ twf,
                                                       const float* __restrict__ coefA,
                                                       const float* __restrict__ coefB,
                                                       double* __restrict__ pA,
                                                       double* __restrict__ pB) {
  const int b = blockIdx.x, pc = blockIdx.y, tid = threadIdx.x;
  const int i = tid & 31, g = tid >> 5;
  const size_t base = (size_t)b * CS * CK + (size_t)pc * 512;
  double aA = 0.0, aB = 0.0;
  for (int e = g; e < 512; e += 8) {
    const double w = (double)twf[base + e];
    int id = idxp[base + e];
    id = (id >= 0 && id < CN) ? id : 0;
    aA += w * (double)coefA[id * CNB + i];
    aB += w * (double)coefB[id * CNB + i];
  }
  __shared__ double rA[8][32], rB[8][32];
  rA[g][i] = aA; rB[g][i] = aB;
  __syncthreads();
  if (tid < 32) {
    double ta = 0.0, tb = 0.0;
#pragma unroll
    for (int g2 = 0; g2 < 8; ++g2) { ta += rA[g2][tid]; tb += rB[g2][tid]; }
    pA[((size_t)b * 32 + pc) * 32 + tid] = ta;
    pB[((size_t)b * 32 + pc) * 32 + tid] = tb;
  }
}

__global__ __launch_bounds__(256) void sab_final_kernel(const double* __restrict__ pA,
                                                        const double* __restrict__ pB,
                                                        const double* __restrict__ bs,
                                                        float* __restrict__ sA,
                                                        float* __restrict__ sB) {
  const int tid = threadIdx.x;
  const int b = tid >> 5, i = tid & 31;
  double ta = 0.0, tb = 0.0;
  for (int p = 0; p < 32; ++p) {
    ta += pA[((size_t)b * 32 + p) * 32 + i];
    tb += pB[((size_t)b * 32 + p) * 32 + i];
  }
  const double inv = 1.0 / (bs[b] + 1e-8);
  sA[b * CNB + i] = (float)(ta * inv);
  sB[b * CNB + i] = (float)(tb * inv);
}

// ---------------- A[b,:] = sum_i s[b,i]*basis[i,:] ----------------
__global__ __launch_bounds__(256) void amat_kernel(const float* __restrict__ sA,
                                                   const float* __restrict__ basis,
                                                   float* __restrict__ Am, int inner) {
  const int dr = blockIdx.x * 256 + threadIdx.x;
  __shared__ float ssa[CB * CNB];
  if (threadIdx.x < CB * CNB) ssa[threadIdx.x] = sA[threadIdx.x];
  __syncthreads();
  float acc[CB] = {};
  for (int i = 0; i < CNB; ++i) {
    const float bv = basis[(size_t)i * inner + dr];
#pragma unroll
    for (int b = 0; b < CB; ++b) acc[b] = fmaf(ssa[b * CNB + i], bv, acc[b]);
  }
#pragma unroll
  for (int b = 0; b < CB; ++b) Am[(size_t)b * inner + dr] = acc[b];
}

// ---------------- transpose + f32->bf16: WT[n][k] = bf16(W[k][n]) ----------------
__global__ __launch_bounds__(256) void transp_bf16_kernel(const float* __restrict__ W,
                                                          unsigned short* __restrict__ WT,
                                                          int K, int N) {
  const int k0 = blockIdx.x * 32, n0 = blockIdx.y * 32;
  __shared__ float t[32][33];
  const int tid = threadIdx.x;
  const int r = tid >> 3, c4 = (tid & 7) * 4;
  const float4 v = *reinterpret_cast<const float4*>(W + (size_t)(k0 + r) * N + n0 + c4);
  t[r][c4] = v.x; t[r][c4 + 1] = v.y; t[r][c4 + 2] = v.z; t[r][c4 + 3] = v.w;
  __syncthreads();
  unsigned short* op = WT + (size_t)(n0 + r) * K + k0 + c4;
  op[0] = f2bf(t[c4][r]); op[1] = f2bf(t[c4 + 1][r]);
  op[2] = f2bf(t[c4 + 2][r]); op[3] = f2bf(t[c4 + 3][r]);
}

// ---------------- bf16 MFMA GEMM: A f32 [M][K], BT bf16 [N][K] ----------------
// EPI: 0 -> Op = acc; 3 -> Op = relu(acc+bias); 4 -> Op += 0.1*(acc+bias); 5 -> ofin = aux+acc+bias
template <int EPI>
__global__ __launch_bounds__(256) void gemm_bf16_kernel(
    const float* __restrict__ A, const unsigned short* __restrict__ BT,
    float* __restrict__ Op, const float* __restrict__ bias,
    const float* __restrict__ aux, float* __restrict__ ofin, int Kd, int Nc) {
  const int bn = blockIdx.x * 64, bm = blockIdx.y * 64;
  const int tid = threadIdx.x, lane = tid & 63, wid = tid >> 6;
  const int wm = wid >> 1, wn = wid & 1, l15 = lane & 15, l4 = lane >> 4;
  __shared__ unsigned short as[64][40];
  __shared__ unsigned short bs[64][40];
  f32x4v acc[2][2] = {};
  const int sr = tid >> 2, sk = (tid & 3) * 8;
  for (int k0 = 0; k0 < Kd; k0 += 32) {
    const float4* ap = reinterpret_cast<const float4*>(A + (size_t)(bm + sr) * Kd + k0 + sk);
    const float4 a0 = ap[0], a1 = ap[1];
    as[sr][sk + 0] = f2bf(a0.x); as[sr][sk + 1] = f2bf(a0.y);
    as[sr][sk + 2] = f2bf(a0.z); as[sr][sk + 3] = f2bf(a0.w);
    as[sr][sk + 4] = f2bf(a1.x); as[sr][sk + 5] = f2bf(a1.y);
    as[sr][sk + 6] = f2bf(a1.z); as[sr][sk + 7] = f2bf(a1.w);
    *reinterpret_cast<uint4*>(&bs[sr][sk]) =
        *reinterpret_cast<const uint4*>(BT + (size_t)(bn + sr) * Kd + k0 + sk);
    __syncthreads();
    const short8 af0 = *reinterpret_cast<const short8*>(&as[wm * 32 + l15][l4 * 8]);
    const short8 af1 = *reinterpret_cast<const short8*>(&as[wm * 32 + 16 + l15][l4 * 8]);
    const short8 bf0 = *reinterpret_cast<const short8*>(&bs[wn * 32 + l15][l4 * 8]);
    const short8 bf1 = *reinterpret_cast<const short8*>(&bs[wn * 32 + 16 + l15][l4 * 8]);
    acc[0][0] = __builtin_amdgcn_mfma_f32_16x16x32_bf16(af0, bf0, acc[0][0], 0, 0, 0);
    acc[0][1] = __builtin_amdgcn_mfma_f32_16x16x32_bf16(af0, bf1, acc[0][1], 0, 0, 0);
    acc[1][0] = __builtin_amdgcn_mfma_f32_16x16x32_bf16(af1, bf0, acc[1][0], 0, 0, 0);
    acc[1][1] = __builtin_amdgcn_mfma_f32_16x16x32_bf16(af1, bf1, acc[1][1], 0, 0, 0);
    __syncthreads();
  }
#pragma unroll
  for (int i = 0; i < 2; ++i)
#pragma unroll
    for (int j = 0; j < 2; ++j)
#pragma unroll
      for (int b = 0; b < 4; ++b) {
        const int row = bm + wm * 32 + i * 16 + l4 * 4 + b;
        const int col = bn + wn * 32 + j * 16 + l15;
        const float v = acc[i][j][b];
        if (EPI == 0) {
          Op[(size_t)row * Nc + col] = v;
        } else if (EPI == 3) {
          const float vv = v + bias[col];
          Op[(size_t)row * Nc + col] = vv > 0.f ? vv : 0.f;
        } else if (EPI == 4) {
          Op[(size_t)row * Nc + col] += 0.1f * (v + bias[col]);
        } else {
          ofin[(size_t)row * Nc + col] = aux[(size_t)row * Nc + col] + v + bias[col];
        }
      }
}

// ---------------- generic f32 tiled GEMM (EPI 0 plain, 2 gelu) ----------------
template <int EPI>
__global__ __launch_bounds__(256) void gemm_kernel(
    const float* __restrict__ Ap, const float* __restrict__ Bp,
    float* __restrict__ Op, int M, int Kd, int Nc, size_t sA, size_t sB, size_t sO) {
  const int bn = blockIdx.x * 64, bm = blockIdx.y * 64, bz = blockIdx.z;
  const int tid = threadIdx.x, tx = tid & 15, ty = tid >> 4;
  const float* Af = Ap + (size_t)bz * sA;
  const float* Bb = Bp + (size_t)bz * sB;
  __shared__ float as[64][17];
  __shared__ float bs[16][64];
  float acc[4][4] = {};
  const int lr = tid >> 2, lk = (tid & 3) * 4;
  const int br = tid >> 4, bc = (tid & 15) * 4;
  for (int k0 = 0; k0 < Kd; k0 += 16) {
    const float4 a4 = *reinterpret_cast<const float4*>(Af + (size_t)(bm + lr) * Kd + k0 + lk);
    as[lr][lk + 0] = a4.x; as[lr][lk + 1] = a4.y; as[lr][lk + 2] = a4.z; as[lr][lk + 3] = a4.w;
    const float4 b4 = *reinterpret_cast<const float4*>(Bb + (size_t)(k0 + br) * Nc + bn + bc);
    *reinterpret_cast<float4*>(&bs[br][bc]) = b4;
    __syncthreads();
#pragma unroll
    for (int kk = 0; kk < 16; ++kk) {
      float a[4], b[4];
#pragma unroll
      for (int i = 0; i < 4; ++i) a[i] = as[ty * 4 + i][kk];
#pragma unroll
      for (int j = 0; j < 4; ++j) b[j] = bs[kk][tx * 4 + j];
#pragma unroll
      for (int i = 0; i < 4; ++i)
#pragma unroll
        for (int j = 0; j < 4; ++j) acc[i][j] = fmaf(a[i], b[j], acc[i][j]);
    }
    __syncthreads();
  }
#pragma unroll
  for (int i = 0; i < 4; ++i) {
    const int row = bm + ty * 4 + i;
#pragma unroll
    for (int j = 0; j < 4; ++j) {
      const int col = bn + tx * 4 + j;
      const float vacc = acc[i][j];
      if (EPI == 0) {
        Op[(size_t)bz * sO + (size_t)row * Nc + col] = vacc;
      } else if (EPI == 2) {
        Op[(size_t)bz * sO + (size_t)row * Nc + col] =
            0.5f * vacc * (1.0f + erff(vacc * 0.70710678118654752f));
      }
    }
  }
}

// =======================================================================
extern "C" void kernel_launch(void* const* d_in, const int* in_sizes, int n_in,
                              void* d_out, int out_size, void* d_ws, size_t ws_size,
                              hipStream_t stream) {
  const float* x = (const float*)d_in[0];
  const float* g1 = (const float*)d_in[1];
  const float* be1 = (const float*)d_in[2];
  const float* g2 = (const float*)d_in[3];
  const float* be2 = (const float*)d_in[4];
  const float* Wq = (const float*)d_in[5];
  const float* bq = (const float*)d_in[6];
  const float* Wk = (const float*)d_in[7];
  const float* bk = (const float*)d_in[8];
  const float* Wv = (const float*)d_in[9];
  const float* bv = (const float*)d_in[10];
  const float* Wp = (const float*)d_in[11];
  const float* bp = (const float*)d_in[12];
  const float* nA = (const float*)d_in[13];
  const float* nB = (const float*)d_in[14];
  const float* basisA = (const float*)d_in[15];
  const float* basisB = (const float*)d_in[16];
  const float* coefA = (const float*)d_in[17];
  const float* coefB = (const float*)d_in[18];
  const float* Wr1 = (const float*)d_in[19];
  const float* br1 = (const float*)d_in[20];
  const float* Wr2 = (const float*)d_in[21];
  const float* br2 = (const float*)d_in[22];
  const float* Wd = (const float*)d_in[23];
  const float* bd = (const float*)d_in[24];
  float* out = (float*)d_out;

  // --- workspace overlay (224 MiB) ---
  const size_t MB = 1ull << 20;
  if (ws_size < 224 * MB) return;
  char* W = (char*)d_ws;
  double* n64 = (double*)(W + 0 * MB);
  double* ctx64 = (double*)(W + 64 * MB);
  double* neur64 = (double*)(W + 128 * MB);
  double* qkv2 = (double*)(W + 144 * MB);   // 50.3 MB (HP=4), dead after attn loop
  float* scsl = (float*)(W + 144 * MB);
  int* idxp = (int*)(W + 152 * MB);
  float* twf = (float*)(W + 152 * MB + 512 * 1024);
  double* w64 = (double*)(W + 153 * MB);
  double* bsum = (double*)(W + 153 * MB + 256 * 1024);
  float* sA = (float*)(W + 153 * MB + 256 * 1024 + 4096);
  float* sB = (float*)(W + 153 * MB + 256 * 1024 + 8192);
  double* pA = (double*)(W + 153 * MB + 512 * 1024);
  double* pB = (double*)(W + 153 * MB + 512 * 1024 + 64 * 1024);
  float* n2b = (float*)(W + 0 * MB);
  float* hbuf = (float*)(W + 0 * MB);
  float* tsig = (float*)(W + 64 * MB);
  float* Bm = (float*)(W + 156 * MB);
  float* Gb = (float*)(W + 164 * MB);
  float* Am = (float*)(W + 166 * MB);
  unsigned short* Wr1T = (unsigned short*)(W + 168 * MB);
  unsigned short* Wr2T = (unsigned short*)(W + 170 * MB);
  unsigned short* WdT = (unsigned short*)(W + 172 * MB);
  float* m32 = (float*)(W + 180 * MB);
  float* x1b = (float*)(W + 180 * MB);
  float* neur32 = (float*)(W + 212 * MB);
  float* hf1 = (float*)(W + 212 * MB);
  unsigned short* nbf = (unsigned short*)(W + 220 * MB);

  // ---- Phase A: f64 router ----
  ln_kernel<double><<<CT, 256, 0, stream>>>(x, g1, be1, n64);
  neurons_kernel<<<dim3(CD / 256, CN), 256, 0, stream>>>(nA, nB, neur64, neur32, nbf);
  for (int hp = 0; hp < CD / CDH / HP; ++hp) {
    const int h0 = hp * HP;
    qkv64_z<<<dim3(HP, CT / 64), 768, 0, stream>>>(n64, Wq, Wk, Wv, bq, bk, bv, h0, qkv2);
    attn64_v2<<<dim3(CS / 64, CB, HP), 256, 0, stream>>>(qkv2, h0, ctx64);
  }
  wgate_kernel<<<CT, 256, 0, stream>>>(n64, ctx64, Wp, bp, w64);
  mcomb_kernel<<<CT, 256, 0, stream>>>(n64, ctx64, w64, m32);
  // weight prep (regions [168,180) are free only after the attn loop)
  transp_bf16_kernel<<<dim3(CFF / 32, CD / 32), 256, 0, stream>>>(Wd, WdT, CFF, CD);
  transp_bf16_kernel<<<dim3(CRH / 32, CFF / 32), 256, 0, stream>>>(Wr2, Wr2T, CRH, CFF);
  transp_bf16_kernel<<<dim3(CD / 32, CRH / 32), 256, 0, stream>>>(Wr1, Wr1T, CD, CRH);
  for (int t0 = 0; t0 < CT; t0 += SLICE) {
    gemm_bf16_kernel<0><<<dim3(CN / 64, SLICE / 64), 256, 0, stream>>>(
        m32 + (size_t)t0 * CD, nbf, scsl, nullptr, nullptr, nullptr, CD, CN);
    topk2_kernel<<<SLICE, 256, 0, stream>>>(scsl, t0, n64, neur64, idxp, twf);
  }

  // ---- Phase B: FFN ----
  bsum_kernel<<<CB, 256, 0, stream>>>(twf, bsum);
  x1_kernel<<<CT, 256, 0, stream>>>(x, idxp, twf, neur32, x1b, tsig);
  ln_kernel<float><<<CT, 256, 0, stream>>>(x1b, g2, be2, n2b);
  sab_part_kernel<<<dim3(CB, 32), 256, 0, stream>>>(idxp, twf, coefA, coefB, pA, pB);
  sab_final_kernel<<<1, 256, 0, stream>>>(pA, pB, bsum, sA, sB);
  amat_kernel<<<(CD * CBR) / 256, 256, 0, stream>>>(sA, basisA, Am, CD * CBR);
  amat_kernel<<<(CBR * CFF) / 256, 256, 0, stream>>>(sB, basisB, Bm, CBR * CFF);
  gemm_kernel<0><<<dim3(CBR / 64, CS / 64, CB), 256, 0, stream>>>(
      n2b, Am, Gb, CS, CD, CBR, (size_t)CS * CD, (size_t)CD * CBR, (size_t)CS * CBR);
  gemm_bf16_kernel<3><<<dim3(CRH / 64, CT / 64), 256, 0, stream>>>(
      tsig, Wr1T, hf1, br1, nullptr, nullptr, CD, CRH);
  gemm_kernel<2><<<dim3(CFF / 64, CS / 64, CB), 256, 0, stream>>>(
      Gb, Bm, hbuf, CS, CBR, CFF, (size_t)CS * CBR, (size_t)CBR * CFF, (size_t)CS * CFF);
  gemm_bf16_kernel<4><<<dim3(CFF / 64, CT / 64), 256, 0, stream>>>(
      hf1, Wr2T, hbuf, br2, nullptr, nullptr, CRH, CFF);
  gemm_bf16_kernel<5><<<dim3(CD / 64, CT / 64), 256, 0, stream>>>(
      hbuf, WdT, nullptr, bd, x1b, out, CFF, CD);
  idxout_kernel<<<(CT * CK + 255) / 256, 256, 0, stream>>>(idxp, out);
}